// Round 12
// baseline (64.503 us; speedup 1.0000x reference)
//
#include <hip/hip_runtime.h>
#include <hip/hip_bf16.h>
#include <math.h>

#define NH 16
#define SL 2048
#define DM 128

typedef float f32x4 __attribute__((ext_vector_type(4)));
typedef short s16x8 __attribute__((ext_vector_type(8)));
typedef short s16x4 __attribute__((ext_vector_type(4)));
typedef int   i32x4 __attribute__((ext_vector_type(4)));

static __device__ __forceinline__ unsigned short f2bfu(float f) {
  __hip_bfloat16 h = __float2bfloat16(f);
  return (unsigned short)__builtin_bit_cast(short, h);
}
static __device__ __forceinline__ short f2bf(float f) {
  __hip_bfloat16 h = __float2bfloat16(f);
  return __builtin_bit_cast(short, h);
}
static __device__ __forceinline__ unsigned pack2(float lo, float hi) {
  return (unsigned)f2bfu(lo) | ((unsigned)f2bfu(hi) << 16);
}
static __device__ __forceinline__ float bf2f(short s) {
  unsigned u = ((unsigned)(unsigned short)s) << 16;
  return __builtin_bit_cast(float, u);
}

// 8-wave block = 128 q-rows (wave w: rows q0+16w+col). KV tile 64. K row-major
// bf16 swizzled + V^T swizzled, DOUBLE-buffered (64KB LDS -> 2 blocks/CU),
// reg-staged: loads for t+1 issued before t's compute, converts+ds_writes
// after, ONE barrier per tile. Swapped QK^T; P->PV in-register via shuffles;
// defer-max; interior-tile mask skip; fp32 acc.
// mode=1 (grid 384): chains split to <=4 tiles, ALL blocks co-resident;
// partial (bf16 acc -> pacc, m/l stash in out cols 0..3), merged by attn_merge.
// mode=0 (grid 256): no split, direct epilogue (ws fallback).
__global__ __launch_bounds__(512, 4) void attn_part(
    const float* __restrict__ qg,
    const float* __restrict__ kg,
    const float* __restrict__ vg,
    const int* __restrict__ offs, int n_off,
    float* __restrict__ out,
    char* __restrict__ pacc, int mode)
{
  __shared__ __align__(16) char Kb[2][16384];
  __shared__ __align__(16) char Vb[2][16384];

  const int t    = threadIdx.x;     // 0..511
  const int lane = t & 63;
  const int w    = t >> 6;          // 0..7
  const int col  = lane & 15;
  const int g    = lane >> 4;

  const int b = blockIdx.x;
  const int h = b & 15;
  int qb, z;
  bool split;
  if (mode) {
    const int s   = b >> 4;                       // 0..23
    const int doc = s & 3;
    const int j   = s >> 2;                       // 0..5, chain-desc order
    const int wd  = (0x012233 >> (4 * j)) & 15;   // [3,3,2,2,1,0]
    const int zz  = (0x221010 >> (4 * j)) & 15;   // [0,1,0,1,2,2]; 2 = unsplit
    qb    = doc * 4 + wd;
    split = (zz != 2);
    z     = zz & 1;
  } else {
    qb = 15 - ((b >> 4) & 15);
    split = false;
    z = 0;
  }
  const int q0 = qb * 128;

  const float* qh = qg + (size_t)h * SL * DM;
  const float* kh = kg + (size_t)h * SL * DM;
  const float* vh = vg + (size_t)h * SL * DM;

  const float scale = 0.08838834764831843f; // 1/sqrt(128)

  const int qrow = q0 + 16 * w + col;

  // offsets: parallel predicated loads (sorted ascending -> max of o<=pos)
  int ov[8];
  #pragma unroll
  for (int ii = 0; ii < 8; ++ii) ov[ii] = (ii < n_off) ? offs[ii] : 0x7fffffff;
  int qstart = 0, kv_lo = 0;
  #pragma unroll
  for (int ii = 0; ii < 8; ++ii) {
    if (ov[ii] <= qrow) qstart = max(qstart, ov[ii]);
    if (ov[ii] <= q0)   kv_lo  = max(kv_lo, ov[ii]);
  }
  const int n = ((q0 + 128) - kv_lo) >> 6;  // total KV tiles for this q-block

  int tA = 0, tN = n;
  if (split) {
    const int nA = (n + 1) >> 1;
    if (z) { tA = nA; tN = n - nA; } else { tN = nA; }
  }
  const int kvb = kv_lo + (tA << 6);        // this block's KV base

  // Q fragment, pre-scaled. Lane holds [row=col][k=8g+j] per 32-k group kk.
  s16x8 qf[4];
  #pragma unroll
  for (int kk = 0; kk < 4; ++kk) {
    const float* qp = qh + (size_t)qrow * DM + 32 * kk + 8 * g;
    f32x4 lo = *(const f32x4*)qp;
    f32x4 hi = *(const f32x4*)(qp + 4);
    s16x8 f;
    f[0] = f2bf(lo[0] * scale); f[1] = f2bf(lo[1] * scale);
    f[2] = f2bf(lo[2] * scale); f[3] = f2bf(lo[3] * scale);
    f[4] = f2bf(hi[0] * scale); f[5] = f2bf(hi[1] * scale);
    f[6] = f2bf(hi[2] * scale); f[7] = f2bf(hi[3] * scale);
    qf[kk] = f;
  }

  f32x4 acc[8];
  #pragma unroll
  for (int dt = 0; dt < 8; ++dt) { f32x4 zv = {0.f, 0.f, 0.f, 0.f}; acc[dt] = zv; }
  float m_ = -1e30f, l_ = 0.f;

  // staging (512 threads): grp=t>>5 (0..15), cols d0..d0+3.
  // K rows grp+16i (i<4); V rows grp*4+j (j<4) -> V^T.
  const int d0  = (t & 31) * 4;
  const int grp = t >> 5;
  const int rot = (t >> 1) & 3;
  f32x4 kr[4], vr[4];

#define LOADT(T) do {                                                         \
    const float* _ks = kh + (size_t)(kvb + ((T) << 6)) * DM;                  \
    const float* _vs = vh + (size_t)(kvb + ((T) << 6)) * DM;                  \
    _Pragma("unroll")                                                         \
    for (int _i = 0; _i < 4; ++_i)                                            \
      kr[_i] = *(const f32x4*)(_ks + (size_t)(grp + 16 * _i) * DM + d0);      \
    _Pragma("unroll")                                                         \
    for (int _j = 0; _j < 4; ++_j)                                            \
      vr[_j] = *(const f32x4*)(_vs + (size_t)(grp * 4 + _j) * DM + d0);       \
  } while (0)

#define WRITEKV(B) do {                                                       \
    _Pragma("unroll")                                                         \
    for (int _i = 0; _i < 4; ++_i) {                                          \
      int _r = grp + 16 * _i;                                                 \
      s16x4 _b;                                                               \
      _b[0] = f2bf(kr[_i][0]); _b[1] = f2bf(kr[_i][1]);                       \
      _b[2] = f2bf(kr[_i][2]); _b[3] = f2bf(kr[_i][3]);                       \
      *(s16x4*)(&Kb[B][0] + ((_r * 256 + d0 * 2) ^ ((_r & 7) << 4))) = _b;    \
    }                                                                         \
    _Pragma("unroll")                                                         \
    for (int _di = 0; _di < 4; ++_di) {                                       \
      int _dd = (_di + rot) & 3;                                              \
      int _d  = d0 + _dd;                                                     \
      s16x4 _b;                                                               \
      _b[0] = f2bf(vr[0][_dd]); _b[1] = f2bf(vr[1][_dd]);                     \
      _b[2] = f2bf(vr[2][_dd]); _b[3] = f2bf(vr[3][_dd]);                     \
      *(s16x4*)(&Vb[B][0] + ((_d * 128 + grp * 8) ^ ((_d & 7) << 4))) = _b;   \
    }                                                                         \
  } while (0)

  // prologue: stage tile 0 into buffer 0
  LOADT(0);
  WRITEKV(0);
  int cur = 0;

  // P-shuffle source lanes: target (col,g) pulls from col+32*(g&1) and +16
  const int srcA = col + 32 * (g & 1);
  const int srcB = srcA + 16;
  const bool hi2 = (g >> 1) != 0;

  for (int it = 0; it < tN; ++it) {
    const int kv0 = kvb + (it << 6);
    __syncthreads();                       // release writes, acquire buf[cur]

    const bool pre = (it + 1 < tN);
    if (pre) LOADT(it + 1);                // issue next-tile global loads early
    __builtin_amdgcn_sched_barrier(0);     // pin loads before compute

    // ---- QK^T (swapped): st[kt] = K_tile_kt . Q^T -> S^T[k][q] ----
    f32x4 st[4];
    #pragma unroll
    for (int kt = 0; kt < 4; ++kt) { f32x4 zv = {0.f, 0.f, 0.f, 0.f}; st[kt] = zv; }
    __builtin_amdgcn_s_setprio(1);
    #pragma unroll
    for (int kt = 0; kt < 4; ++kt) {
      int row = kt * 16 + col;
      #pragma unroll
      for (int kk = 0; kk < 4; ++kk) {
        s16x8 kf = *(const s16x8*)(&Kb[cur][0] + ((row * 256 + 64 * kk + 16 * g) ^ ((row & 7) << 4)));
        st[kt] = __builtin_amdgcn_mfma_f32_16x16x32_bf16(kf, qf[kk], st[kt], 0, 0, 0);
      }
    }
    __builtin_amdgcn_s_setprio(0);

    // ---- mask (skipped for interior tiles) + online softmax ----
    const bool needmask = __any((kv0 + 63 > qrow) || (kv0 < qstart));
    if (needmask) {
      #pragma unroll
      for (int kt = 0; kt < 4; ++kt) {
        #pragma unroll
        for (int r = 0; r < 4; ++r) {
          int kpos = kv0 + kt * 16 + 4 * g + r;
          bool ok = (kpos <= qrow) && (kpos >= qstart);
          st[kt][r] = ok ? st[kt][r] : -3.0e38f;
        }
      }
    }
    float cm = -3.0e38f;
    #pragma unroll
    for (int kt = 0; kt < 4; ++kt) {
      #pragma unroll
      for (int r = 0; r < 4; ++r) cm = fmaxf(cm, st[kt][r]);
    }
    cm = fmaxf(cm, __shfl_xor(cm, 16));
    cm = fmaxf(cm, __shfl_xor(cm, 32));
    float mn = fmaxf(m_, cm);
    float al = 1.f;
    if (!__all(cm <= m_)) {               // defer-max: skip rescale if no growth
      al = __expf(m_ - mn);
      m_ = mn;
      #pragma unroll
      for (int r = 0; r < 4; ++r) {
        float ar = __shfl(al, 4 * g + r);
        #pragma unroll
        for (int dt = 0; dt < 8; ++dt) acc[dt][r] *= ar;
      }
    }
    float psum = 0.f;
    unsigned w01[4], w23[4];
    #pragma unroll
    for (int kt = 0; kt < 4; ++kt) {
      float p0 = __expf(st[kt][0] - mn);
      float p1 = __expf(st[kt][1] - mn);
      float p2 = __expf(st[kt][2] - mn);
      float p3 = __expf(st[kt][3] - mn);
      psum += (p0 + p1) + (p2 + p3);
      w01[kt] = pack2(p0, p1);
      w23[kt] = pack2(p2, p3);
    }
    psum += __shfl_xor(psum, 16);
    psum += __shfl_xor(psum, 32);
    l_ = l_ * al + psum;

    // ---- PV: A-frag assembled in-register via shuffles; acc += P . V ----
    __builtin_amdgcn_s_setprio(1);
    #pragma unroll
    for (int ksel = 0; ksel < 2; ++ksel) {
      unsigned a0 = __shfl(w01[2 * ksel], srcA);
      unsigned a1 = __shfl(w01[2 * ksel + 1], srcA);
      unsigned b0 = __shfl(w23[2 * ksel], srcA);
      unsigned b1 = __shfl(w23[2 * ksel + 1], srcA);
      unsigned c0 = __shfl(w01[2 * ksel], srcB);
      unsigned c1 = __shfl(w01[2 * ksel + 1], srcB);
      unsigned e0 = __shfl(w23[2 * ksel], srcB);
      unsigned e1 = __shfl(w23[2 * ksel + 1], srcB);
      i32x4 uu;
      uu[0] = (int)(hi2 ? a1 : a0);
      uu[1] = (int)(hi2 ? b1 : b0);
      uu[2] = (int)(hi2 ? c1 : c0);
      uu[3] = (int)(hi2 ? e1 : e0);
      s16x8 pa = __builtin_bit_cast(s16x8, uu);
      #pragma unroll
      for (int dt = 0; dt < 8; ++dt) {
        int d = dt * 16 + col;
        s16x8 vf = *(const s16x8*)(&Vb[cur][0] + ((d * 128 + 64 * ksel + 16 * g) ^ ((d & 7) << 4)));
        acc[dt] = __builtin_amdgcn_mfma_f32_16x16x32_bf16(pa, vf, acc[dt], 0, 0, 0);
      }
    }
    __builtin_amdgcn_s_setprio(0);

    // ---- convert + write next tile into the other buffer ----
    if (pre) WRITEKV(cur ^ 1);
    cur ^= 1;
  }
#undef LOADT
#undef WRITEKV

  if (!split) {
    // ---- direct epilogue: divide by l, store fp32 ----
    #pragma unroll
    for (int r = 0; r < 4; ++r) {
      float lr  = __shfl(l_, 4 * g + r);
      float inv = 1.f / lr;
      int row   = q0 + 16 * w + 4 * g + r;
      float* op = out + ((size_t)h * SL + row) * DM + col;
      #pragma unroll
      for (int dt = 0; dt < 8; ++dt) op[dt * 16] = acc[dt][r] * inv;
    }
  } else {
    // ---- partial epilogue: unnormalized acc (bf16) -> pacc; (m,l) stash ----
    char* pb = pacc + ((((size_t)(h * 16 + qb)) * 2 + z) << 15);
    #pragma unroll
    for (int r = 0; r < 4; ++r) {
      int row128 = 16 * w + 4 * g + r;
      #pragma unroll
      for (int dt = 0; dt < 8; ++dt)
        *(unsigned short*)(pb + (row128 * 128 + dt * 16 + col) * 2) = f2bfu(acc[dt][r]);
    }
    if (g == 0) {
      int row = q0 + 16 * w + col;
      *(float2*)(out + ((size_t)h * SL + row) * DM + 2 * z) = make_float2(m_, l_);
    }
  }
}

// Merge split q-blocks (n>=5). Grid 256 = 16h x 16qb; early-return otherwise.
// Thread t: row r=t>>1 (0..127), cols (t&1)*64..+63.
__global__ __launch_bounds__(256) void attn_merge(
    const int* __restrict__ offs, int n_off,
    const char* __restrict__ pacc, float* __restrict__ out)
{
  const int t  = threadIdx.x;
  const int h  = blockIdx.x & 15;
  const int qb = blockIdx.x >> 4;
  const int q0 = qb * 128;

  int ov[8];
  #pragma unroll
  for (int ii = 0; ii < 8; ++ii) ov[ii] = (ii < n_off) ? offs[ii] : 0x7fffffff;
  int kv_lo = 0;
  #pragma unroll
  for (int ii = 0; ii < 8; ++ii) if (ov[ii] <= q0) kv_lo = max(kv_lo, ov[ii]);
  const int n = ((q0 + 128) - kv_lo) >> 6;
  if (n < 5) return;                        // not split; out already final

  const int r  = t >> 1;
  const int c0 = (t & 1) * 64;
  float* orow = out + ((size_t)h * SL + q0 + r) * DM;

  float4 s = *(const float4*)orow;          // mA,lA,mB,lB stash
  __syncthreads();                          // all stash reads before any write
  float m  = fmaxf(s.x, s.z);
  float eA = __expf(s.x - m), eB = __expf(s.z - m);
  float inv = 1.f / (eA * s.y + eB * s.w);
  float fa = eA * inv, fb = eB * inv;

  const char* pA = pacc + (((size_t)(h * 16 + qb)) * 2 << 15);
  const char* pB = pA + 32768;
  #pragma unroll
  for (int j = 0; j < 8; ++j) {
    int off = (r * 128 + c0 + j * 8) * 2;
    s16x8 a  = *(const s16x8*)(pA + off);
    s16x8 bq = *(const s16x8*)(pB + off);
    f32x4 o0, o1;
    #pragma unroll
    for (int e = 0; e < 4; ++e) o0[e] = bf2f(a[e]) * fa + bf2f(bq[e]) * fb;
    #pragma unroll
    for (int e = 0; e < 4; ++e) o1[e] = bf2f(a[4 + e]) * fa + bf2f(bq[4 + e]) * fb;
    *(f32x4*)(orow + c0 + j * 8)     = o0;
    *(f32x4*)(orow + c0 + j * 8 + 4) = o1;
  }
}

extern "C" void kernel_launch(void* const* d_in, const int* in_sizes, int n_in,
                              void* d_out, int out_size, void* d_ws, size_t ws_size,
                              hipStream_t stream) {
  const float* q = (const float*)d_in[0];
  const float* k = (const float*)d_in[1];
  const float* v = (const float*)d_in[2];
  const int* offs = (const int*)d_in[3];
  const int n_off = in_sizes[3];
  float* out = (float*)d_out;

  const size_t need = (size_t)NH * 16 * 2 * 32768;   // 16,777,216 B
  if (ws_size >= need) {
    attn_part<<<384, 512, 0, stream>>>(q, k, v, offs, n_off, out, (char*)d_ws, 1);
    attn_merge<<<256, 256, 0, stream>>>(offs, n_off, (const char*)d_ws, out);
  } else {
    attn_part<<<256, 512, 0, stream>>>(q, k, v, offs, n_off, out, (char*)d_ws, 0);
  }
}

// Round 13
// 40.281 us; speedup vs baseline: 1.6014x; 1.6014x over previous
//
#include <hip/hip_runtime.h>
#include <hip/hip_bf16.h>
#include <math.h>

#define NH 16
#define SL 2048
#define DM 128

typedef float f32x4 __attribute__((ext_vector_type(4)));
typedef short s16x8 __attribute__((ext_vector_type(8)));
typedef short s16x4 __attribute__((ext_vector_type(4)));
typedef int   i32x4 __attribute__((ext_vector_type(4)));

static __device__ __forceinline__ unsigned short f2bfu(float f) {
  __hip_bfloat16 h = __float2bfloat16(f);
  return (unsigned short)__builtin_bit_cast(short, h);
}
static __device__ __forceinline__ short f2bf(float f) {
  __hip_bfloat16 h = __float2bfloat16(f);
  return __builtin_bit_cast(short, h);
}
static __device__ __forceinline__ unsigned pack2(float lo, float hi) {
  return (unsigned)f2bfu(lo) | ((unsigned)f2bfu(hi) << 16);
}

// 4-wave block = 64 q-rows (wave w: rows q0+16w..+15). KV tile 64. K row-major
// bf16 swizzled (double-buffered) + V^T swizzled (TRIPLE-buffered) = 80KB LDS
// -> 2 blocks/CU. Reg-staged: loads for t+1 issued at iter top, converts+
// ds_writes late. ONE barrier per tile. 1-deep pipeline: PV(t-1) runs
// alongside QK(t) (independent MFMA clusters, different LDS buffers, P in
// registers), softmax(t) overlaps the stage-writes. fp32 acc.
// Complementary block pairing: co-resident blocks sum to 9 tiles.
__global__ __launch_bounds__(256) void attn_pipe(
    const float* __restrict__ qg,
    const float* __restrict__ kg,
    const float* __restrict__ vg,
    const int* __restrict__ offs, int n_off,
    float* __restrict__ out)
{
  __shared__ __align__(16) char Kb[2][16384];
  __shared__ __align__(16) char Vb[3][16384];

  const int t    = threadIdx.x;
  const int lane = t & 63;
  const int w    = t >> 6;
  const int col  = lane & 15;
  const int g    = lane >> 4;

  // complementary pairing: blocks b (z=0: 8-u tiles) and b+256 (z=1: u+1) pair to 9
  const int blk = blockIdx.x;
  const int z   = blk >> 8;
  const int y   = (blk >> 4) & 15;
  const int h   = blk & 15;
  const int dno = y >> 2, u = y & 3;
  const int p   = z ? u : 7 - u;
  const int q0  = (dno * 8 + p) * 64;

  const float* qh = qg + (size_t)h * SL * DM;
  const float* kh = kg + (size_t)h * SL * DM;
  const float* vh = vg + (size_t)h * SL * DM;

  const float scale = 0.08838834764831843f; // 1/sqrt(128)

  const int qrow = q0 + 16 * w + col;

  // offsets: parallel predicated loads (sorted ascending -> max of o<=pos)
  int ov[8];
  #pragma unroll
  for (int ii = 0; ii < 8; ++ii) ov[ii] = (ii < n_off) ? offs[ii] : 0x7fffffff;
  int qstart = 0, kv_lo = 0;
  #pragma unroll
  for (int ii = 0; ii < 8; ++ii) {
    if (ov[ii] <= qrow) qstart = max(qstart, ov[ii]);
    if (ov[ii] <= q0)   kv_lo  = max(kv_lo, ov[ii]);
  }
  const int n = ((q0 + 64) - kv_lo) >> 6;  // KV tiles for this block

  // Q fragment, pre-scaled. Lane holds [row=col][k=8g+j] per 32-k group kk.
  s16x8 qf[4];
  #pragma unroll
  for (int kk = 0; kk < 4; ++kk) {
    const float* qp = qh + (size_t)qrow * DM + 32 * kk + 8 * g;
    f32x4 lo = *(const f32x4*)qp;
    f32x4 hi = *(const f32x4*)(qp + 4);
    s16x8 f;
    f[0] = f2bf(lo[0] * scale); f[1] = f2bf(lo[1] * scale);
    f[2] = f2bf(lo[2] * scale); f[3] = f2bf(lo[3] * scale);
    f[4] = f2bf(hi[0] * scale); f[5] = f2bf(hi[1] * scale);
    f[6] = f2bf(hi[2] * scale); f[7] = f2bf(hi[3] * scale);
    qf[kk] = f;
  }

  f32x4 acc[8];
  #pragma unroll
  for (int dt = 0; dt < 8; ++dt) { f32x4 zv = {0.f, 0.f, 0.f, 0.f}; acc[dt] = zv; }
  float m_ = -1e30f, l_ = 0.f;

  // staging: thread covers K rows r0+8i (cols d0..d0+3) and V rows r0*4+32k+j
  const int d0  = (t & 31) * 4;
  const int r0  = t >> 5;
  const int rot = (t >> 1) & 3;
  f32x4 kr[8], vr[8];

#define LOADT(T) do {                                                         \
    const float* _ks = kh + (size_t)(kv_lo + ((T) << 6)) * DM;                \
    const float* _vs = vh + (size_t)(kv_lo + ((T) << 6)) * DM;                \
    _Pragma("unroll")                                                         \
    for (int _i = 0; _i < 8; ++_i)                                            \
      kr[_i] = *(const f32x4*)(_ks + (size_t)(r0 + 8 * _i) * DM + d0);        \
    _Pragma("unroll")                                                         \
    for (int _k = 0; _k < 2; ++_k) {                                          \
      _Pragma("unroll")                                                       \
      for (int _j = 0; _j < 4; ++_j)                                          \
        vr[_k * 4 + _j] =                                                     \
          *(const f32x4*)(_vs + (size_t)(r0 * 4 + 32 * _k + _j) * DM + d0);   \
    }                                                                         \
  } while (0)

#define WRITEKV(KB, VB) do {                                                  \
    _Pragma("unroll")                                                         \
    for (int _i = 0; _i < 8; ++_i) {                                          \
      int _r = r0 + 8 * _i;                                                   \
      s16x4 _b;                                                               \
      _b[0] = f2bf(kr[_i][0]); _b[1] = f2bf(kr[_i][1]);                       \
      _b[2] = f2bf(kr[_i][2]); _b[3] = f2bf(kr[_i][3]);                       \
      *(s16x4*)((KB) + ((_r * 256 + d0 * 2) ^ ((_r & 7) << 4))) = _b;         \
    }                                                                         \
    _Pragma("unroll")                                                         \
    for (int _k = 0; _k < 2; ++_k) {                                          \
      int _k0 = r0 * 4 + 32 * _k;                                             \
      _Pragma("unroll")                                                       \
      for (int _di = 0; _di < 4; ++_di) {                                     \
        int _dd = (_di + rot) & 3;                                            \
        int _d  = d0 + _dd;                                                   \
        s16x4 _b;                                                             \
        _b[0] = f2bf(vr[_k * 4 + 0][_dd]); _b[1] = f2bf(vr[_k * 4 + 1][_dd]); \
        _b[2] = f2bf(vr[_k * 4 + 2][_dd]); _b[3] = f2bf(vr[_k * 4 + 3][_dd]); \
        *(s16x4*)((VB) + ((_d * 128 + _k0 * 2) ^ ((_d & 7) << 4))) = _b;      \
      }                                                                       \
    }                                                                         \
  } while (0)

  // prologue: stage tile 0 into K buffer 0 / V buffer 0
  LOADT(0);
  WRITEKV(&Kb[0][0], &Vb[0][0]);
  int ck = 0, cv = 0;

  // P-shuffle source lanes: target (col,g) pulls from col+32*(g&1) and +16
  const int srcA = col + 32 * (g & 1);
  const int srcB = srcA + 16;
  const bool hi2 = (g >> 1) != 0;

  s16x8 paF0, paF1;   // P fragments of tile t-1 (pipelined PV)

  for (int it = 0; it < n; ++it) {
    const int kv0 = kv_lo + (it << 6);
    __syncthreads();                       // buf[ck]/buf[cv] hold tile it

    const bool pre = (it + 1 < n);
    if (pre) LOADT(it + 1);                // issue next-tile global loads early
    __builtin_amdgcn_sched_barrier(0);     // pin loads before compute

    const int pv = (cv == 0) ? 2 : cv - 1; // V buffer of tile it-1
    const int nv = (cv == 2) ? 0 : cv + 1; // V buffer for tile it+1

    // ---- QK^T(t)  [MFMA cluster 1, Kb[ck]] ----
    f32x4 st[4];
    #pragma unroll
    for (int kt = 0; kt < 4; ++kt) { f32x4 zv = {0.f, 0.f, 0.f, 0.f}; st[kt] = zv; }
    __builtin_amdgcn_s_setprio(1);
    #pragma unroll
    for (int kt = 0; kt < 4; ++kt) {
      int row = kt * 16 + col;
      #pragma unroll
      for (int kk = 0; kk < 4; ++kk) {
        s16x8 kf = *(const s16x8*)(&Kb[ck][0] + ((row * 256 + 64 * kk + 16 * g) ^ ((row & 7) << 4)));
        st[kt] = __builtin_amdgcn_mfma_f32_16x16x32_bf16(kf, qf[kk], st[kt], 0, 0, 0);
      }
    }

    // ---- PV(t-1)  [MFMA cluster 2, Vb[pv], pa in registers] ----
    if (it > 0) {
      #pragma unroll
      for (int dt = 0; dt < 8; ++dt) {
        int d = dt * 16 + col;
        s16x8 vf0 = *(const s16x8*)(&Vb[pv][0] + ((d * 128 + 16 * g) ^ ((d & 7) << 4)));
        acc[dt] = __builtin_amdgcn_mfma_f32_16x16x32_bf16(paF0, vf0, acc[dt], 0, 0, 0);
        s16x8 vf1 = *(const s16x8*)(&Vb[pv][0] + ((d * 128 + 64 + 16 * g) ^ ((d & 7) << 4)));
        acc[dt] = __builtin_amdgcn_mfma_f32_16x16x32_bf16(paF1, vf1, acc[dt], 0, 0, 0);
      }
    }
    __builtin_amdgcn_s_setprio(0);

    // ---- stage-write tile t+1 (overlaps softmax below in scheduler) ----
    if (pre) WRITEKV(&Kb[ck ^ 1][0], &Vb[nv][0]);

    // ---- mask (skipped for interior tiles) + online softmax(t) ----
    const bool needmask = __any((kv0 + 63 > qrow) || (kv0 < qstart));
    if (needmask) {
      #pragma unroll
      for (int kt = 0; kt < 4; ++kt) {
        #pragma unroll
        for (int r = 0; r < 4; ++r) {
          int kpos = kv0 + kt * 16 + 4 * g + r;
          bool ok = (kpos <= qrow) && (kpos >= qstart);
          st[kt][r] = ok ? st[kt][r] : -3.0e38f;
        }
      }
    }
    float cm = -3.0e38f;
    #pragma unroll
    for (int kt = 0; kt < 4; ++kt) {
      #pragma unroll
      for (int r = 0; r < 4; ++r) cm = fmaxf(cm, st[kt][r]);
    }
    cm = fmaxf(cm, __shfl_xor(cm, 16));
    cm = fmaxf(cm, __shfl_xor(cm, 32));
    float mn = fmaxf(m_, cm);
    float al = __expf(m_ - mn);
    m_ = mn;
    float psum = 0.f;
    unsigned w01[4], w23[4];
    #pragma unroll
    for (int kt = 0; kt < 4; ++kt) {
      float p0 = __expf(st[kt][0] - mn);
      float p1 = __expf(st[kt][1] - mn);
      float p2 = __expf(st[kt][2] - mn);
      float p3 = __expf(st[kt][3] - mn);
      psum += (p0 + p1) + (p2 + p3);
      w01[kt] = pack2(p0, p1);
      w23[kt] = pack2(p2, p3);
    }
    psum += __shfl_xor(psum, 16);
    psum += __shfl_xor(psum, 32);
    l_ = l_ * al + psum;

    // ---- rescale O by alpha (after PV(t-1) was added) ----
    #pragma unroll
    for (int r = 0; r < 4; ++r) {
      float ar = __shfl(al, 4 * g + r);
      #pragma unroll
      for (int dt = 0; dt < 8; ++dt) acc[dt][r] *= ar;
    }

    // ---- build P fragments for PV(t) (consumed next iteration) ----
    {
      unsigned a0 = __shfl(w01[0], srcA);
      unsigned a1 = __shfl(w01[1], srcA);
      unsigned b0 = __shfl(w23[0], srcA);
      unsigned b1 = __shfl(w23[1], srcA);
      unsigned c0 = __shfl(w01[0], srcB);
      unsigned c1 = __shfl(w01[1], srcB);
      unsigned e0 = __shfl(w23[0], srcB);
      unsigned e1 = __shfl(w23[1], srcB);
      i32x4 uu;
      uu[0] = (int)(hi2 ? a1 : a0);
      uu[1] = (int)(hi2 ? b1 : b0);
      uu[2] = (int)(hi2 ? c1 : c0);
      uu[3] = (int)(hi2 ? e1 : e0);
      paF0 = __builtin_bit_cast(s16x8, uu);
      a0 = __shfl(w01[2], srcA);
      a1 = __shfl(w01[3], srcA);
      b0 = __shfl(w23[2], srcA);
      b1 = __shfl(w23[3], srcA);
      c0 = __shfl(w01[2], srcB);
      c1 = __shfl(w01[3], srcB);
      e0 = __shfl(w23[2], srcB);
      e1 = __shfl(w23[3], srcB);
      uu[0] = (int)(hi2 ? a1 : a0);
      uu[1] = (int)(hi2 ? b1 : b0);
      uu[2] = (int)(hi2 ? c1 : c0);
      uu[3] = (int)(hi2 ? e1 : e0);
      paF1 = __builtin_bit_cast(s16x8, uu);
    }

    ck ^= 1;
    cv = nv;
  }
#undef LOADT
#undef WRITEKV

  // ---- epilogue: final PV(n-1), divide by l, store fp32 ----
  {
    const int pv = (cv == 0) ? 2 : cv - 1;  // V buffer of tile n-1
    __builtin_amdgcn_s_setprio(1);
    #pragma unroll
    for (int dt = 0; dt < 8; ++dt) {
      int d = dt * 16 + col;
      s16x8 vf0 = *(const s16x8*)(&Vb[pv][0] + ((d * 128 + 16 * g) ^ ((d & 7) << 4)));
      acc[dt] = __builtin_amdgcn_mfma_f32_16x16x32_bf16(paF0, vf0, acc[dt], 0, 0, 0);
      s16x8 vf1 = *(const s16x8*)(&Vb[pv][0] + ((d * 128 + 64 + 16 * g) ^ ((d & 7) << 4)));
      acc[dt] = __builtin_amdgcn_mfma_f32_16x16x32_bf16(paF1, vf1, acc[dt], 0, 0, 0);
    }
    __builtin_amdgcn_s_setprio(0);
  }
  #pragma unroll
  for (int r = 0; r < 4; ++r) {
    float lr  = __shfl(l_, 4 * g + r);
    float inv = 1.f / lr;
    int row   = q0 + 16 * w + 4 * g + r;
    float* op = out + ((size_t)h * SL + row) * DM + col;
    #pragma unroll
    for (int dt = 0; dt < 8; ++dt) op[dt * 16] = acc[dt][r] * inv;
  }
}

extern "C" void kernel_launch(void* const* d_in, const int* in_sizes, int n_in,
                              void* d_out, int out_size, void* d_ws, size_t ws_size,
                              hipStream_t stream) {
  const float* q = (const float*)d_in[0];
  const float* k = (const float*)d_in[1];
  const float* v = (const float*)d_in[2];
  const int* offs = (const int*)d_in[3];
  const int n_off = in_sizes[3];
  float* out = (float*)d_out;

  const int blocks = NH * (SL / 64); // 512
  attn_pipe<<<blocks, 256, 0, stream>>>(q, k, v, offs, n_off, out);
}

// Round 14
// 28.425 us; speedup vs baseline: 2.2693x; 1.4171x over previous
//
#include <hip/hip_runtime.h>
#include <hip/hip_bf16.h>
#include <math.h>

#define NH 16
#define SL 2048
#define DM 128

typedef float f32x4 __attribute__((ext_vector_type(4)));
typedef short s16x8 __attribute__((ext_vector_type(8)));
typedef short s16x4 __attribute__((ext_vector_type(4)));
typedef int   i32x4 __attribute__((ext_vector_type(4)));

static __device__ __forceinline__ unsigned short f2bfu(float f) {
  __hip_bfloat16 h = __float2bfloat16(f);
  return (unsigned short)__builtin_bit_cast(short, h);
}
static __device__ __forceinline__ short f2bf(float f) {
  __hip_bfloat16 h = __float2bfloat16(f);
  return __builtin_bit_cast(short, h);
}
static __device__ __forceinline__ unsigned pack2(float lo, float hi) {
  return (unsigned)f2bfu(lo) | ((unsigned)f2bfu(hi) << 16);
}

// R7/R8 structure (best measured: 29.3us), micro-optimized only.
// 4-wave block = 64 q-rows. KV tile 64, K row-major bf16 swizzled + V^T
// swizzled, double-buffered (64KB LDS). Reg-staged: loads for t+1 issued
// before t's compute, converts+ds_writes after, ONE barrier per tile.
// Swapped QK^T -> S^T; softmax in exp2 domain (Q pre-scaled by scale*log2e);
// interior-tile mask skip; defer-max (THR=0, exactly safe); P->PV in-register
// via shuffles; fp32 acc. Complementary block pairing (pairs sum to 9 tiles).
__global__ __launch_bounds__(256) void attn_dbuf(
    const float* __restrict__ qg,
    const float* __restrict__ kg,
    const float* __restrict__ vg,
    const int* __restrict__ offs, int n_off,
    float* __restrict__ out)
{
  __shared__ __align__(16) char Kb[2][16384];
  __shared__ __align__(16) char Vb[2][16384];

  const int t    = threadIdx.x;
  const int lane = t & 63;
  const int w    = t >> 6;
  const int col  = lane & 15;
  const int g    = lane >> 4;

  // complementary pairing: blocks b (z=0: 8-u tiles) and b+256 (z=1: u+1) pair to 9
  const int blk = blockIdx.x;
  const int z   = blk >> 8;
  const int y   = (blk >> 4) & 15;
  const int h   = blk & 15;
  const int dno = y >> 2, u = y & 3;
  const int p   = z ? u : 7 - u;
  const int q0  = (dno * 8 + p) * 64;

  const float* qh = qg + (size_t)h * SL * DM;
  const float* kh = kg + (size_t)h * SL * DM;
  const float* vh = vg + (size_t)h * SL * DM;

  // 1/sqrt(128) * log2(e): QK^T lands directly in exp2 domain
  const float scale2 = 0.08838834764831843f * 1.4426950408889634f;

  const int qrow = q0 + 16 * w + col;

  // offsets: parallel predicated loads (sorted ascending -> max of o<=pos)
  int ov[8];
  #pragma unroll
  for (int ii = 0; ii < 8; ++ii) ov[ii] = (ii < n_off) ? offs[ii] : 0x7fffffff;
  int qstart = 0, kv_lo = 0;
  #pragma unroll
  for (int ii = 0; ii < 8; ++ii) {
    if (ov[ii] <= qrow) qstart = max(qstart, ov[ii]);
    if (ov[ii] <= q0)   kv_lo  = max(kv_lo, ov[ii]);
  }
  const int n = ((q0 + 64) - kv_lo) >> 6;  // KV tiles for this block

  // Q fragment, pre-scaled. Lane holds [row=col][k=8g+j] per 32-k group kk.
  s16x8 qf[4];
  #pragma unroll
  for (int kk = 0; kk < 4; ++kk) {
    const float* qp = qh + (size_t)qrow * DM + 32 * kk + 8 * g;
    f32x4 lo = *(const f32x4*)qp;
    f32x4 hi = *(const f32x4*)(qp + 4);
    s16x8 f;
    f[0] = f2bf(lo[0] * scale2); f[1] = f2bf(lo[1] * scale2);
    f[2] = f2bf(lo[2] * scale2); f[3] = f2bf(lo[3] * scale2);
    f[4] = f2bf(hi[0] * scale2); f[5] = f2bf(hi[1] * scale2);
    f[6] = f2bf(hi[2] * scale2); f[7] = f2bf(hi[3] * scale2);
    qf[kk] = f;
  }

  f32x4 acc[8];
  #pragma unroll
  for (int dt = 0; dt < 8; ++dt) { f32x4 zv = {0.f, 0.f, 0.f, 0.f}; acc[dt] = zv; }
  float m_ = -1e30f, l_ = 0.f;

  // staging: thread covers K rows r0+8i (cols d0..d0+3) and V rows r0*4+32k+j
  const int d0  = (t & 31) * 4;
  const int r0  = t >> 5;
  const int rot = (t >> 1) & 3;
  f32x4 kr[8], vr[8];

#define LOADT(T) do {                                                         \
    const float* _ks = kh + (size_t)(kv_lo + ((T) << 6)) * DM;                \
    const float* _vs = vh + (size_t)(kv_lo + ((T) << 6)) * DM;                \
    _Pragma("unroll")                                                         \
    for (int _i = 0; _i < 8; ++_i)                                            \
      kr[_i] = *(const f32x4*)(_ks + (size_t)(r0 + 8 * _i) * DM + d0);        \
    _Pragma("unroll")                                                         \
    for (int _k = 0; _k < 2; ++_k) {                                          \
      _Pragma("unroll")                                                       \
      for (int _j = 0; _j < 4; ++_j)                                          \
        vr[_k * 4 + _j] =                                                     \
          *(const f32x4*)(_vs + (size_t)(r0 * 4 + 32 * _k + _j) * DM + d0);   \
    }                                                                         \
  } while (0)

#define WRITEKV(B) do {                                                       \
    _Pragma("unroll")                                                         \
    for (int _i = 0; _i < 8; ++_i) {                                          \
      int _r = r0 + 8 * _i;                                                   \
      s16x4 _b;                                                               \
      _b[0] = f2bf(kr[_i][0]); _b[1] = f2bf(kr[_i][1]);                       \
      _b[2] = f2bf(kr[_i][2]); _b[3] = f2bf(kr[_i][3]);                       \
      *(s16x4*)(&Kb[B][0] + ((_r * 256 + d0 * 2) ^ ((_r & 7) << 4))) = _b;    \
    }                                                                         \
    _Pragma("unroll")                                                         \
    for (int _k = 0; _k < 2; ++_k) {                                          \
      int _k0 = r0 * 4 + 32 * _k;                                             \
      _Pragma("unroll")                                                       \
      for (int _di = 0; _di < 4; ++_di) {                                     \
        int _dd = (_di + rot) & 3;                                            \
        int _d  = d0 + _dd;                                                   \
        s16x4 _b;                                                             \
        _b[0] = f2bf(vr[_k * 4 + 0][_dd]); _b[1] = f2bf(vr[_k * 4 + 1][_dd]); \
        _b[2] = f2bf(vr[_k * 4 + 2][_dd]); _b[3] = f2bf(vr[_k * 4 + 3][_dd]); \
        *(s16x4*)(&Vb[B][0] + ((_d * 128 + _k0 * 2) ^ ((_d & 7) << 4))) = _b; \
      }                                                                       \
    }                                                                         \
  } while (0)

  // prologue: stage tile 0 into buffer 0
  LOADT(0);
  WRITEKV(0);
  int cur = 0;

  // P-shuffle source lanes: target (col,g) pulls from col+32*(g&1) and +16
  const int srcA = col + 32 * (g & 1);
  const int srcB = srcA + 16;
  const bool hi2 = (g >> 1) != 0;

  for (int it = 0; it < n; ++it) {
    const int kv0 = kv_lo + (it << 6);
    __syncthreads();                       // release writes, acquire buf[cur]

    const bool pre = (it + 1 < n);
    if (pre) LOADT(it + 1);                // issue next-tile global loads early
    __builtin_amdgcn_sched_barrier(0);     // pin loads before compute

    // ---- QK^T (swapped): st[kt] = K_tile_kt . Q^T -> S^T[k][q] (exp2 dom) ----
    f32x4 st[4];
    #pragma unroll
    for (int kt = 0; kt < 4; ++kt) { f32x4 zv = {0.f, 0.f, 0.f, 0.f}; st[kt] = zv; }
    __builtin_amdgcn_s_setprio(1);
    #pragma unroll
    for (int kt = 0; kt < 4; ++kt) {
      int row = kt * 16 + col;
      #pragma unroll
      for (int kk = 0; kk < 4; ++kk) {
        s16x8 kf = *(const s16x8*)(&Kb[cur][0] + ((row * 256 + 64 * kk + 16 * g) ^ ((row & 7) << 4)));
        st[kt] = __builtin_amdgcn_mfma_f32_16x16x32_bf16(kf, qf[kk], st[kt], 0, 0, 0);
      }
    }
    __builtin_amdgcn_s_setprio(0);

    // ---- mask (skipped for interior tiles) + online softmax (exp2) ----
    const bool needmask = __any((kv0 + 63 > qrow) || (kv0 < qstart));
    if (needmask) {
      #pragma unroll
      for (int kt = 0; kt < 4; ++kt) {
        #pragma unroll
        for (int r = 0; r < 4; ++r) {
          int kpos = kv0 + kt * 16 + 4 * g + r;
          bool ok = (kpos <= qrow) && (kpos >= qstart);
          st[kt][r] = ok ? st[kt][r] : -3.0e38f;
        }
      }
    }
    float cm = -3.0e38f;
    #pragma unroll
    for (int kt = 0; kt < 4; ++kt) {
      #pragma unroll
      for (int r = 0; r < 4; ++r) cm = fmaxf(cm, st[kt][r]);
    }
    cm = fmaxf(cm, __shfl_xor(cm, 16));
    cm = fmaxf(cm, __shfl_xor(cm, 32));
    float al = 1.f;
    float mn = m_;
    if (!__all(cm <= m_)) {                // defer-max: skip rescale if no growth
      mn = fmaxf(m_, cm);
      al = __builtin_amdgcn_exp2f(m_ - mn);
      m_ = mn;
      #pragma unroll
      for (int r = 0; r < 4; ++r) {
        float ar = __shfl(al, 4 * g + r);
        #pragma unroll
        for (int dt = 0; dt < 8; ++dt) acc[dt][r] *= ar;
      }
    }
    float psum = 0.f;
    unsigned w01[4], w23[4];
    #pragma unroll
    for (int kt = 0; kt < 4; ++kt) {
      float p0 = __builtin_amdgcn_exp2f(st[kt][0] - mn);
      float p1 = __builtin_amdgcn_exp2f(st[kt][1] - mn);
      float p2 = __builtin_amdgcn_exp2f(st[kt][2] - mn);
      float p3 = __builtin_amdgcn_exp2f(st[kt][3] - mn);
      psum += (p0 + p1) + (p2 + p3);
      w01[kt] = pack2(p0, p1);
      w23[kt] = pack2(p2, p3);
    }
    psum += __shfl_xor(psum, 16);
    psum += __shfl_xor(psum, 32);
    l_ = l_ * al + psum;

    // ---- PV: A-frag assembled in-register via shuffles; acc += P . V ----
    __builtin_amdgcn_s_setprio(1);
    #pragma unroll
    for (int ksel = 0; ksel < 2; ++ksel) {
      unsigned a0 = __shfl(w01[2 * ksel], srcA);
      unsigned a1 = __shfl(w01[2 * ksel + 1], srcA);
      unsigned b0 = __shfl(w23[2 * ksel], srcA);
      unsigned b1 = __shfl(w23[2 * ksel + 1], srcA);
      unsigned c0 = __shfl(w01[2 * ksel], srcB);
      unsigned c1 = __shfl(w01[2 * ksel + 1], srcB);
      unsigned e0 = __shfl(w23[2 * ksel], srcB);
      unsigned e1 = __shfl(w23[2 * ksel + 1], srcB);
      i32x4 uu;
      uu[0] = (int)(hi2 ? a1 : a0);
      uu[1] = (int)(hi2 ? b1 : b0);
      uu[2] = (int)(hi2 ? c1 : c0);
      uu[3] = (int)(hi2 ? e1 : e0);
      s16x8 pa = __builtin_bit_cast(s16x8, uu);
      #pragma unroll
      for (int dt = 0; dt < 8; ++dt) {
        int d = dt * 16 + col;
        s16x8 vf = *(const s16x8*)(&Vb[cur][0] + ((d * 128 + 64 * ksel + 16 * g) ^ ((d & 7) << 4)));
        acc[dt] = __builtin_amdgcn_mfma_f32_16x16x32_bf16(pa, vf, acc[dt], 0, 0, 0);
      }
    }
    __builtin_amdgcn_s_setprio(0);

    // ---- convert + write next tile into the other buffer ----
    if (pre) WRITEKV(cur ^ 1);
    cur ^= 1;
  }
#undef LOADT
#undef WRITEKV

  // ---- epilogue: divide by l, store fp32 ----
  #pragma unroll
  for (int r = 0; r < 4; ++r) {
    float lr  = __shfl(l_, 4 * g + r);
    float inv = 1.f / lr;
    int row   = q0 + 16 * w + 4 * g + r;
    float* op = out + ((size_t)h * SL + row) * DM + col;
    #pragma unroll
    for (int dt = 0; dt < 8; ++dt) op[dt * 16] = acc[dt][r] * inv;
  }
}

extern "C" void kernel_launch(void* const* d_in, const int* in_sizes, int n_in,
                              void* d_out, int out_size, void* d_ws, size_t ws_size,
                              hipStream_t stream) {
  const float* q = (const float*)d_in[0];
  const float* k = (const float*)d_in[1];
  const float* v = (const float*)d_in[2];
  const int* offs = (const int*)d_in[3];
  const int n_off = in_sizes[3];
  float* out = (float*)d_out;

  const int blocks = NH * (SL / 64); // 512
  attn_dbuf<<<blocks, 256, 0, stream>>>(q, k, v, offs, n_off, out);
}